// Round 23
// baseline (156.761 us; speedup 1.0000x reference)
//
#include <hip/hip_runtime.h>
#include <hip/hip_bf16.h>

#define N_TAG 128
#define T_LEN 512
#define START_TAG 126
#define STOP_TAG 127

typedef __attribute__((ext_vector_type(8))) __bf16 bf16x8;
typedef __attribute__((ext_vector_type(4))) float f32x4;
typedef __attribute__((ext_vector_type(4))) int i32x4;

// Round 23 = r22 (134us, absmax 32) + PACKB via explicit v_cvt_pk_bf16_f32
// (16 pk-converts/step instead of 32 scalar (__bf16) casts + vector asm).
// Rationale: 1 wave/SIMD -> issue-serialized; VALUBusy 33% ~= 530cy/step.
// If hipcc lowers (__bf16) casts to software RNE (~4 ops each), PACKB is
// ~200-260cy/step; cvt_pk is RNE -> bit-identical, pure issue-count win.
__global__ __launch_bounds__(320, 1)
void crf_split_kernel(const float* __restrict__ feats,
                      const float* __restrict__ trans,
                      const int* __restrict__ tags,
                      float* __restrict__ out) {
  const int tid = threadIdx.x;
  const int wid = tid >> 6;
  const int lane = tid & 63;
  const int bbase = blockIdx.x * 2;

  __shared__ float Uf[2][N_TAG];
  __shared__ float Wb[2][N_TAG];
  __shared__ float LZ[4];
  __shared__ float GOLD[2];

  if (wid == 4) {
    // ---- gold wave: lanes 0-31 batch 0, lanes 32-63 batch 1 ----
    const int half = lane >> 5, tl = lane & 31;
    const int b = bbase + half;
    const int* tg = tags + (size_t)b * T_LEN;
    const float* fg = feats + (size_t)b * T_LEN * N_TAG;
    float gsum = 0.f;
    for (int t = tl; t < T_LEN; t += 32) {
      int tag = tg[t];
      int prev = (t == 0) ? START_TAG : tg[t - 1];
      gsum += trans[(size_t)tag * N_TAG + prev] + fg[(size_t)t * N_TAG + tag];
      if (t == T_LEN - 1) gsum += trans[STOP_TAG * N_TAG + tag];
    }
#pragma unroll
    for (int s = 16; s; s >>= 1) gsum += __shfl_xor(gsum, s);
    if (tl == 0) GOLD[half] = gsum;
    __syncthreads();
    // ---- combine ----
#pragma unroll
    for (int bL = 0; bL < 2; ++bL) {
      float sd = Uf[bL][lane] * Wb[bL][lane] +
                 Uf[bL][lane + 64] * Wb[bL][lane + 64];
#pragma unroll
      for (int s = 32; s; s >>= 1) sd += __shfl_xor(sd, s);
      if (lane == 0)
        out[bbase + bL] = __logf(sd) + LZ[2 * bL] + LZ[2 * bL + 1] - GOLD[bL];
    }
    return;
  }

  // ---- main DP waves: wid = 2*bL + dir (dir 0 fwd, 1 bwd) ----
  const int bL = wid >> 1, dir = wid & 1;
  const int batch = bbase + bL;
  const int n = lane & 15, g = lane >> 4;
  const float* fbase = feats + (size_t)batch * T_LEN * N_TAG;
  const int T0 = dir ? 510 : 0;
  const int TS = dir ? -1 : 1;
  const int ib = 32 * g;  // bpermute base byte address

  // ---- A fragments: tile mt holds E rows tau(mt, ridx); lane supplies
  //      row ridx=n, elements k = 32kk+8g+j. fwd: E[tau][k]; bwd: E[k][tau].
  bf16x8 A[8][4];
#pragma unroll
  for (int mt = 0; mt < 8; ++mt) {
    const int tau = 32 * (mt >> 1) + 8 * (n >> 2) + 4 * (mt & 1) + (n & 3);
#pragma unroll
    for (int kk = 0; kk < 4; ++kk) {
      bf16x8 v;
      if (dir == 0) {
        const float* p = trans + (size_t)tau * N_TAG + 32 * kk + 8 * g;
        f32x4 x = *(const f32x4*)p;
        f32x4 y = *(const f32x4*)(p + 4);
        v[0] = (__bf16)__expf(x[0]); v[1] = (__bf16)__expf(x[1]);
        v[2] = (__bf16)__expf(x[2]); v[3] = (__bf16)__expf(x[3]);
        v[4] = (__bf16)__expf(y[0]); v[5] = (__bf16)__expf(y[1]);
        v[6] = (__bf16)__expf(y[2]); v[7] = (__bf16)__expf(y[3]);
      } else {
#pragma unroll
        for (int j = 0; j < 8; ++j)
          v[j] = (__bf16)__expf(trans[(size_t)(32 * kk + 8 * g + j) * N_TAG + tau]);
      }
      A[mt][kk] = v;
    }
  }

  // ---- B init ----
  bf16x8 Bv[4];
#pragma unroll
  for (int kk = 0; kk < 4; ++kk) {
    bf16x8 z;
#pragma unroll
    for (int j = 0; j < 8; ++j) z[j] = (__bf16)0.0f;
    Bv[kk] = z;
  }
  if (dir == 0) {
    // u_{-1} = one-hot(START=126): tag 126 -> kk=3, g=3, j=6
    if (g == 3) Bv[3][6] = (__bf16)1.0f;
  } else {
    // b0 = ef_511 ⊙ s, s_j = exp(trans[STOP][j]); tag = 32kk+8g+j
    const float* s127 = trans + (size_t)STOP_TAG * N_TAG;
    const float* f511 = fbase + (size_t)(T_LEN - 1) * N_TAG;
#pragma unroll
    for (int kk = 0; kk < 4; ++kk) {
      const int off = 32 * kk + 8 * g;
      f32x4 s0 = *(const f32x4*)(s127 + off);
      f32x4 s1 = *(const f32x4*)(s127 + off + 4);
      f32x4 e0 = *(const f32x4*)(f511 + off);
      f32x4 e1 = *(const f32x4*)(f511 + off + 4);
      bf16x8 v;
      v[0] = (__bf16)__expf(s0[0] + e0[0]); v[1] = (__bf16)__expf(s0[1] + e0[1]);
      v[2] = (__bf16)__expf(s0[2] + e0[2]); v[3] = (__bf16)__expf(s0[3] + e0[3]);
      v[4] = (__bf16)__expf(s1[0] + e1[0]); v[5] = (__bf16)__expf(s1[1] + e1[1]);
      v[6] = (__bf16)__expf(s1[2] + e1[2]); v[7] = (__bf16)__expf(s1[3] + e1[3]);
      Bv[kk] = v;
    }
  }

  // ---- feat ring: slot s holds raw rows (t==s mod 4), 2 dwords/lane.
  //      Pk[s] = packed bf16 pair (exp(raw0) | exp(raw1)<<16), built at the
  //      old exp point (1 iter before use). ----
  float Lr[4][2];
  int Pk[4];
#pragma unroll
  for (int s = 0; s < 4; ++s) {
    const float* rp = fbase + (size_t)(T0 + TS * s) * N_TAG;
    Lr[s][0] = rp[lane];
    Lr[s][1] = rp[lane + 64];
  }
  {
    float e0 = __expf(Lr[0][0]);
    float e1 = __expf(Lr[0][1]);
    asm("v_cvt_pk_bf16_f32 %0, %1, %2" : "=v"(Pk[0]) : "v"(e0), "v"(e1));
  }
  float logZ = 0.0f;

  // EF[2a+bb][r] = ef[tau(a,bb,r)], tau = 32a+8g+4bb+r. Pair fetch: one
  // bpermute at lane (32*a2+8g+4bb+r) of Pk returns lo=ef[tau(a2)] and
  // hi=ef[tau(a2)+64]=ef[tau(a2+2)] -> 16 bpermutes cover all 32 values.
#define BPERM(DST, SLOT)                                                     \
  {                                                                          \
    _Pragma("unroll") for (int a2 = 0; a2 < 2; ++a2) {                       \
      _Pragma("unroll") for (int bb = 0; bb < 2; ++bb) {                     \
        _Pragma("unroll") for (int r = 0; r < 4; ++r) {                      \
          int w_ = __builtin_amdgcn_ds_bpermute(                             \
              ib + 128 * a2 + 16 * bb + 4 * r, Pk[SLOT]);                    \
          DST[2 * a2 + bb][r] = __int_as_float(w_ << 16);                    \
          DST[4 + 2 * a2 + bb][r] =                                          \
              __int_as_float((int)(w_ & 0xffff0000u));                       \
        }                                                                    \
      }                                                                      \
    }                                                                        \
  }

#define RENORM(ACC)                                                          \
  {                                                                          \
    float mx_ = ACC[0][0];                                                   \
    _Pragma("unroll") for (int mt = 0; mt < 8; ++mt)                         \
        mx_ = fmaxf(mx_, fmaxf(fmaxf(ACC[mt][0], ACC[mt][1]),                \
                               fmaxf(ACC[mt][2], ACC[mt][3])));              \
    mx_ = fmaxf(mx_, __shfl_xor(mx_, 16));                                   \
    mx_ = fmaxf(mx_, __shfl_xor(mx_, 32));                                   \
    int eb_ = __float_as_int(mx_) & 0x7f800000;                              \
    float inv_ = __int_as_float(0x7f000000 - eb_); /* exact 2^-a */          \
    logZ += (float)((eb_ >> 23) - 127) * 0.69314718056f;                     \
    _Pragma("unroll") for (int mt = 0; mt < 8; ++mt) {                       \
      ACC[mt][0] *= inv_; ACC[mt][1] *= inv_;                                \
      ACC[mt][2] *= inv_; ACC[mt][3] *= inv_;                                \
    }                                                                        \
  }

  // PACKB: Bv[kk] <- {pk(acc[2kk][0..1]), pk(acc[2kk][2..3]),
  //                   pk(acc[2kk+1][0..1]), pk(acc[2kk+1][2..3])}
  // v_cvt_pk_bf16_f32 is RNE (same as (__bf16) cast) -> bit-identical.
#define PACKB(ACC)                                                           \
  {                                                                          \
    _Pragma("unroll") for (int kk = 0; kk < 4; ++kk) {                       \
      union { i32x4 i; bf16x8 b; } u_;                                       \
      asm("v_cvt_pk_bf16_f32 %0, %1, %2"                                     \
          : "=v"(u_.i[0]) : "v"(ACC[2 * kk][0]), "v"(ACC[2 * kk][1]));       \
      asm("v_cvt_pk_bf16_f32 %0, %1, %2"                                     \
          : "=v"(u_.i[1]) : "v"(ACC[2 * kk][2]), "v"(ACC[2 * kk][3]));       \
      asm("v_cvt_pk_bf16_f32 %0, %1, %2"                                     \
          : "=v"(u_.i[2]) : "v"(ACC[2 * kk + 1][0]), "v"(ACC[2 * kk + 1][1]));\
      asm("v_cvt_pk_bf16_f32 %0, %1, %2"                                     \
          : "=v"(u_.i[3]) : "v"(ACC[2 * kk + 1][2]), "v"(ACC[2 * kk + 1][3]));\
      Bv[kk] = u_.b;                                                         \
    }                                                                        \
  }

#define ITER(S, SX, KP4, DOREN)                                              \
  {                                                                          \
    f32x4 EF[8];                                                             \
    BPERM(EF, S);                                                            \
    f32x4 acc[8];                                                            \
    _Pragma("unroll") for (int mt = 0; mt < 8; ++mt)                         \
        acc[mt] = (f32x4){0.f, 0.f, 0.f, 0.f};                               \
    _Pragma("unroll") for (int kk = 0; kk < 4; ++kk) {                       \
      _Pragma("unroll") for (int mt = 0; mt < 8; ++mt)                       \
          acc[mt] = __builtin_amdgcn_mfma_f32_16x16x32_bf16(                 \
              A[mt][kk], Bv[kk], acc[mt], 0, 0, 0);                          \
    }                                                                        \
    _Pragma("unroll") for (int mt = 0; mt < 8; ++mt) {                       \
      acc[mt][0] *= EF[mt][0]; acc[mt][1] *= EF[mt][1];                      \
      acc[mt][2] *= EF[mt][2]; acc[mt][3] *= EF[mt][3];                      \
    }                                                                        \
    if (DOREN) RENORM(acc);                                                  \
    PACKB(acc);                                                              \
    {                                                                        \
      float e0_ = __expf(Lr[SX][0]); /* next step's ef (landed 3 iters ago)*/\
      float e1_ = __expf(Lr[SX][1]);                                         \
      asm("v_cvt_pk_bf16_f32 %0, %1, %2"                                     \
          : "=v"(Pk[SX]) : "v"(e0_), "v"(e1_));                              \
    }                                                                        \
    {                                                                        \
      const float* rp_ = fbase + (size_t)(T0 + TS * (KP4)) * N_TAG;          \
      Lr[S][0] = rp_[lane]; /* refill slot: 4-iter lookahead */              \
      Lr[S][1] = rp_[lane + 64];                                             \
    }                                                                        \
  }

  // ---- 255 full steps + tail: 256 MFMA steps total ----
  for (int kb = 0; kb < 63; ++kb) {
    const int k0 = kb * 4;
    ITER(0, 1, k0 + 4, false);
    ITER(1, 2, k0 + 5, false);
    ITER(2, 3, k0 + 6, false);
    ITER(3, 0, k0 + 7, true);
  }
  ITER(0, 1, 256, false);  // k=252
  ITER(1, 2, 257, false);  // k=253
  ITER(2, 3, 258, false);  // k=254

  // ---- tail (k=255): fwd multiplies ef_255; bwd keeps raw E^T·b ----
  f32x4 upF[8];
  {
    f32x4 EF[8];
    BPERM(EF, 3);
    f32x4 acc[8];
#pragma unroll
    for (int mt = 0; mt < 8; ++mt) acc[mt] = (f32x4){0.f, 0.f, 0.f, 0.f};
#pragma unroll
    for (int kk = 0; kk < 4; ++kk) {
#pragma unroll
      for (int mt = 0; mt < 8; ++mt)
        acc[mt] = __builtin_amdgcn_mfma_f32_16x16x32_bf16(A[mt][kk], Bv[kk],
                                                          acc[mt], 0, 0, 0);
    }
    if (dir == 0) {
#pragma unroll
      for (int mt = 0; mt < 8; ++mt) {
        acc[mt][0] *= EF[mt][0]; acc[mt][1] *= EF[mt][1];
        acc[mt][2] *= EF[mt][2]; acc[mt][3] *= EF[mt][3];
      }
    }
    RENORM(acc);  // final normalization so the dot can't overflow f32
#pragma unroll
    for (int mt = 0; mt < 8; ++mt) upF[mt] = acc[mt];
  }

  // ---- publish final vectors (plain tag order) ----
  float* dst = (dir == 0) ? Uf[bL] : Wb[bL];
  if (n == 0) {
#pragma unroll
    for (int mt = 0; mt < 8; ++mt) {
      const int base = 32 * (mt >> 1) + 8 * g + 4 * (mt & 1);
#pragma unroll
      for (int r = 0; r < 4; ++r) dst[base + r] = upF[mt][r];
    }
  }
  if (lane == 0) LZ[wid] = logZ;
  __syncthreads();
#undef ITER
#undef PACKB
#undef RENORM
#undef BPERM
}

extern "C" void kernel_launch(void* const* d_in, const int* in_sizes, int n_in,
                              void* d_out, int out_size, void* d_ws, size_t ws_size,
                              hipStream_t stream) {
  const float* feats = (const float*)d_in[0];
  const float* trans = (const float*)d_in[1];
  const int* tags = (const int*)d_in[2];
  float* out = (float*)d_out;
  int B = in_sizes[0] / (T_LEN * N_TAG);  // 512
  crf_split_kernel<<<B / 2, 320, 0, stream>>>(feats, trans, tags, out);
}

// Round 24
// 135.067 us; speedup vs baseline: 1.1606x; 1.1606x over previous
//
#include <hip/hip_runtime.h>
#include <hip/hip_bf16.h>

#define N_TAG 128
#define T_LEN 512
#define START_TAG 126
#define STOP_TAG 127

typedef __attribute__((ext_vector_type(8))) __bf16 bf16x8;
typedef __attribute__((ext_vector_type(4))) float f32x4;

// FINAL (r22, best measured: 134us, absmax 32 << 61.4 threshold).
// Split-direction exp-space CRF DP, zero-communication MFMA steps:
// score = log(s^T ∏ D_t E u0): forward wave computes u_255 (256 steps from
// one-hot START), backward wave computes w = (E^T D_256)...(E^T D_511) s.
// tau(mt,ridx)=32(mt>>1)+8(ridx>>2)+4(mt&1)+(ridx&3) makes each lane's
// C-fragment exactly its next-step B-fragment: no LDS/barriers in the loop.
// EF gather: ring pair (ef[lane], ef[lane+64]) packed to one dword via
// v_cvt_pk_bf16_f32 at the exp point; 16 bpermutes/step (halved DS traffic:
// DS pipe is per-CU, shared by 4 DP waves; r22 A/B: 149->134us).
// PACKB stays as (__bf16) casts — r23 proved hand-asm cvt_pk regresses
// (scheduling pins, m240). Campaign: 7 structural exits all regressed with
// diagnosed causes; this is the serial-dependency floor (1024 chains, 1
// wave/SIMD, ~1300cy/step shared issue stream).
__global__ __launch_bounds__(320, 1)
void crf_split_kernel(const float* __restrict__ feats,
                      const float* __restrict__ trans,
                      const int* __restrict__ tags,
                      float* __restrict__ out) {
  const int tid = threadIdx.x;
  const int wid = tid >> 6;
  const int lane = tid & 63;
  const int bbase = blockIdx.x * 2;

  __shared__ float Uf[2][N_TAG];
  __shared__ float Wb[2][N_TAG];
  __shared__ float LZ[4];
  __shared__ float GOLD[2];

  if (wid == 4) {
    // ---- gold wave: lanes 0-31 batch 0, lanes 32-63 batch 1 ----
    const int half = lane >> 5, tl = lane & 31;
    const int b = bbase + half;
    const int* tg = tags + (size_t)b * T_LEN;
    const float* fg = feats + (size_t)b * T_LEN * N_TAG;
    float gsum = 0.f;
    for (int t = tl; t < T_LEN; t += 32) {
      int tag = tg[t];
      int prev = (t == 0) ? START_TAG : tg[t - 1];
      gsum += trans[(size_t)tag * N_TAG + prev] + fg[(size_t)t * N_TAG + tag];
      if (t == T_LEN - 1) gsum += trans[STOP_TAG * N_TAG + tag];
    }
#pragma unroll
    for (int s = 16; s; s >>= 1) gsum += __shfl_xor(gsum, s);
    if (tl == 0) GOLD[half] = gsum;
    __syncthreads();
    // ---- combine ----
#pragma unroll
    for (int bL = 0; bL < 2; ++bL) {
      float sd = Uf[bL][lane] * Wb[bL][lane] +
                 Uf[bL][lane + 64] * Wb[bL][lane + 64];
#pragma unroll
      for (int s = 32; s; s >>= 1) sd += __shfl_xor(sd, s);
      if (lane == 0)
        out[bbase + bL] = __logf(sd) + LZ[2 * bL] + LZ[2 * bL + 1] - GOLD[bL];
    }
    return;
  }

  // ---- main DP waves: wid = 2*bL + dir (dir 0 fwd, 1 bwd) ----
  const int bL = wid >> 1, dir = wid & 1;
  const int batch = bbase + bL;
  const int n = lane & 15, g = lane >> 4;
  const float* fbase = feats + (size_t)batch * T_LEN * N_TAG;
  const int T0 = dir ? 510 : 0;
  const int TS = dir ? -1 : 1;
  const int ib = 32 * g;  // bpermute base byte address

  // ---- A fragments: tile mt holds E rows tau(mt, ridx); lane supplies
  //      row ridx=n, elements k = 32kk+8g+j. fwd: E[tau][k]; bwd: E[k][tau].
  bf16x8 A[8][4];
#pragma unroll
  for (int mt = 0; mt < 8; ++mt) {
    const int tau = 32 * (mt >> 1) + 8 * (n >> 2) + 4 * (mt & 1) + (n & 3);
#pragma unroll
    for (int kk = 0; kk < 4; ++kk) {
      bf16x8 v;
      if (dir == 0) {
        const float* p = trans + (size_t)tau * N_TAG + 32 * kk + 8 * g;
        f32x4 x = *(const f32x4*)p;
        f32x4 y = *(const f32x4*)(p + 4);
        v[0] = (__bf16)__expf(x[0]); v[1] = (__bf16)__expf(x[1]);
        v[2] = (__bf16)__expf(x[2]); v[3] = (__bf16)__expf(x[3]);
        v[4] = (__bf16)__expf(y[0]); v[5] = (__bf16)__expf(y[1]);
        v[6] = (__bf16)__expf(y[2]); v[7] = (__bf16)__expf(y[3]);
      } else {
#pragma unroll
        for (int j = 0; j < 8; ++j)
          v[j] = (__bf16)__expf(trans[(size_t)(32 * kk + 8 * g + j) * N_TAG + tau]);
      }
      A[mt][kk] = v;
    }
  }

  // ---- B init ----
  bf16x8 Bv[4];
#pragma unroll
  for (int kk = 0; kk < 4; ++kk) {
    bf16x8 z;
#pragma unroll
    for (int j = 0; j < 8; ++j) z[j] = (__bf16)0.0f;
    Bv[kk] = z;
  }
  if (dir == 0) {
    // u_{-1} = one-hot(START=126): tag 126 -> kk=3, g=3, j=6
    if (g == 3) Bv[3][6] = (__bf16)1.0f;
  } else {
    // b0 = ef_511 ⊙ s, s_j = exp(trans[STOP][j]); tag = 32kk+8g+j
    const float* s127 = trans + (size_t)STOP_TAG * N_TAG;
    const float* f511 = fbase + (size_t)(T_LEN - 1) * N_TAG;
#pragma unroll
    for (int kk = 0; kk < 4; ++kk) {
      const int off = 32 * kk + 8 * g;
      f32x4 s0 = *(const f32x4*)(s127 + off);
      f32x4 s1 = *(const f32x4*)(s127 + off + 4);
      f32x4 e0 = *(const f32x4*)(f511 + off);
      f32x4 e1 = *(const f32x4*)(f511 + off + 4);
      bf16x8 v;
      v[0] = (__bf16)__expf(s0[0] + e0[0]); v[1] = (__bf16)__expf(s0[1] + e0[1]);
      v[2] = (__bf16)__expf(s0[2] + e0[2]); v[3] = (__bf16)__expf(s0[3] + e0[3]);
      v[4] = (__bf16)__expf(s1[0] + e1[0]); v[5] = (__bf16)__expf(s1[1] + e1[1]);
      v[6] = (__bf16)__expf(s1[2] + e1[2]); v[7] = (__bf16)__expf(s1[3] + e1[3]);
      Bv[kk] = v;
    }
  }

  // ---- feat ring: slot s holds raw rows (t==s mod 4), 2 dwords/lane.
  //      Pk[s] = packed bf16 pair (exp(raw0) | exp(raw1)<<16), built at the
  //      old exp point (1 iter before use). ----
  float Lr[4][2];
  int Pk[4];
#pragma unroll
  for (int s = 0; s < 4; ++s) {
    const float* rp = fbase + (size_t)(T0 + TS * s) * N_TAG;
    Lr[s][0] = rp[lane];
    Lr[s][1] = rp[lane + 64];
  }
  {
    float e0 = __expf(Lr[0][0]);
    float e1 = __expf(Lr[0][1]);
    asm("v_cvt_pk_bf16_f32 %0, %1, %2" : "=v"(Pk[0]) : "v"(e0), "v"(e1));
  }
  float logZ = 0.0f;

  // EF[2a+bb][r] = ef[tau(a,bb,r)], tau = 32a+8g+4bb+r. Pair fetch: one
  // bpermute at lane (32*a2+8g+4bb+r) of Pk returns lo=ef[tau(a2)] and
  // hi=ef[tau(a2)+64]=ef[tau(a2+2)] -> 16 bpermutes cover all 32 values.
#define BPERM(DST, SLOT)                                                     \
  {                                                                          \
    _Pragma("unroll") for (int a2 = 0; a2 < 2; ++a2) {                       \
      _Pragma("unroll") for (int bb = 0; bb < 2; ++bb) {                     \
        _Pragma("unroll") for (int r = 0; r < 4; ++r) {                      \
          int w_ = __builtin_amdgcn_ds_bpermute(                             \
              ib + 128 * a2 + 16 * bb + 4 * r, Pk[SLOT]);                    \
          DST[2 * a2 + bb][r] = __int_as_float(w_ << 16);                    \
          DST[4 + 2 * a2 + bb][r] =                                          \
              __int_as_float((int)(w_ & 0xffff0000u));                       \
        }                                                                    \
      }                                                                      \
    }                                                                        \
  }

#define RENORM(ACC)                                                          \
  {                                                                          \
    float mx_ = ACC[0][0];                                                   \
    _Pragma("unroll") for (int mt = 0; mt < 8; ++mt)                         \
        mx_ = fmaxf(mx_, fmaxf(fmaxf(ACC[mt][0], ACC[mt][1]),                \
                               fmaxf(ACC[mt][2], ACC[mt][3])));              \
    mx_ = fmaxf(mx_, __shfl_xor(mx_, 16));                                   \
    mx_ = fmaxf(mx_, __shfl_xor(mx_, 32));                                   \
    int eb_ = __float_as_int(mx_) & 0x7f800000;                              \
    float inv_ = __int_as_float(0x7f000000 - eb_); /* exact 2^-a */          \
    logZ += (float)((eb_ >> 23) - 127) * 0.69314718056f;                     \
    _Pragma("unroll") for (int mt = 0; mt < 8; ++mt) {                       \
      ACC[mt][0] *= inv_; ACC[mt][1] *= inv_;                                \
      ACC[mt][2] *= inv_; ACC[mt][3] *= inv_;                                \
    }                                                                        \
  }

#define ITER(S, SX, KP4, DOREN)                                              \
  {                                                                          \
    f32x4 EF[8];                                                             \
    BPERM(EF, S);                                                            \
    f32x4 acc[8];                                                            \
    _Pragma("unroll") for (int mt = 0; mt < 8; ++mt)                         \
        acc[mt] = (f32x4){0.f, 0.f, 0.f, 0.f};                               \
    _Pragma("unroll") for (int kk = 0; kk < 4; ++kk) {                       \
      _Pragma("unroll") for (int mt = 0; mt < 8; ++mt)                       \
          acc[mt] = __builtin_amdgcn_mfma_f32_16x16x32_bf16(                 \
              A[mt][kk], Bv[kk], acc[mt], 0, 0, 0);                          \
    }                                                                        \
    _Pragma("unroll") for (int mt = 0; mt < 8; ++mt) {                       \
      acc[mt][0] *= EF[mt][0]; acc[mt][1] *= EF[mt][1];                      \
      acc[mt][2] *= EF[mt][2]; acc[mt][3] *= EF[mt][3];                      \
    }                                                                        \
    if (DOREN) RENORM(acc);                                                  \
    _Pragma("unroll") for (int kk = 0; kk < 4; ++kk) {                       \
      bf16x8 nb;                                                             \
      nb[0] = (__bf16)acc[2 * kk][0];     nb[1] = (__bf16)acc[2 * kk][1];    \
      nb[2] = (__bf16)acc[2 * kk][2];     nb[3] = (__bf16)acc[2 * kk][3];    \
      nb[4] = (__bf16)acc[2 * kk + 1][0]; nb[5] = (__bf16)acc[2 * kk + 1][1];\
      nb[6] = (__bf16)acc[2 * kk + 1][2]; nb[7] = (__bf16)acc[2 * kk + 1][3];\
      Bv[kk] = nb;                                                           \
    }                                                                        \
    {                                                                        \
      float e0_ = __expf(Lr[SX][0]); /* next step's ef (landed 3 iters ago)*/\
      float e1_ = __expf(Lr[SX][1]);                                         \
      asm("v_cvt_pk_bf16_f32 %0, %1, %2"                                     \
          : "=v"(Pk[SX]) : "v"(e0_), "v"(e1_));                              \
    }                                                                        \
    {                                                                        \
      const float* rp_ = fbase + (size_t)(T0 + TS * (KP4)) * N_TAG;          \
      Lr[S][0] = rp_[lane]; /* refill slot: 4-iter lookahead */              \
      Lr[S][1] = rp_[lane + 64];                                             \
    }                                                                        \
  }

  // ---- 255 full steps + tail: 256 MFMA steps total ----
  for (int kb = 0; kb < 63; ++kb) {
    const int k0 = kb * 4;
    ITER(0, 1, k0 + 4, false);
    ITER(1, 2, k0 + 5, false);
    ITER(2, 3, k0 + 6, false);
    ITER(3, 0, k0 + 7, true);
  }
  ITER(0, 1, 256, false);  // k=252
  ITER(1, 2, 257, false);  // k=253
  ITER(2, 3, 258, false);  // k=254

  // ---- tail (k=255): fwd multiplies ef_255; bwd keeps raw E^T·b ----
  f32x4 upF[8];
  {
    f32x4 EF[8];
    BPERM(EF, 3);
    f32x4 acc[8];
#pragma unroll
    for (int mt = 0; mt < 8; ++mt) acc[mt] = (f32x4){0.f, 0.f, 0.f, 0.f};
#pragma unroll
    for (int kk = 0; kk < 4; ++kk) {
#pragma unroll
      for (int mt = 0; mt < 8; ++mt)
        acc[mt] = __builtin_amdgcn_mfma_f32_16x16x32_bf16(A[mt][kk], Bv[kk],
                                                          acc[mt], 0, 0, 0);
    }
    if (dir == 0) {
#pragma unroll
      for (int mt = 0; mt < 8; ++mt) {
        acc[mt][0] *= EF[mt][0]; acc[mt][1] *= EF[mt][1];
        acc[mt][2] *= EF[mt][2]; acc[mt][3] *= EF[mt][3];
      }
    }
    RENORM(acc);  // final normalization so the dot can't overflow f32
#pragma unroll
    for (int mt = 0; mt < 8; ++mt) upF[mt] = acc[mt];
  }

  // ---- publish final vectors (plain tag order) ----
  float* dst = (dir == 0) ? Uf[bL] : Wb[bL];
  if (n == 0) {
#pragma unroll
    for (int mt = 0; mt < 8; ++mt) {
      const int base = 32 * (mt >> 1) + 8 * g + 4 * (mt & 1);
#pragma unroll
      for (int r = 0; r < 4; ++r) dst[base + r] = upF[mt][r];
    }
  }
  if (lane == 0) LZ[wid] = logZ;
  __syncthreads();
#undef ITER
#undef RENORM
#undef BPERM
}

extern "C" void kernel_launch(void* const* d_in, const int* in_sizes, int n_in,
                              void* d_out, int out_size, void* d_ws, size_t ws_size,
                              hipStream_t stream) {
  const float* feats = (const float*)d_in[0];
  const float* trans = (const float*)d_in[1];
  const int* tags = (const int*)d_in[2];
  float* out = (float*)d_out;
  int B = in_sizes[0] / (T_LEN * N_TAG);  // 512
  crf_split_kernel<<<B / 2, 320, 0, stream>>>(feats, trans, tags, out);
}